// Round 16
// baseline (104.795 us; speedup 1.0000x reference)
//
#include <hip/hip_runtime.h>
#include <hip/hip_bf16.h>
#include <stdint.h>
#include <math.h>

typedef _Float16 half_t;
typedef __attribute__((ext_vector_type(2))) _Float16 h2_t;
typedef __attribute__((ext_vector_type(4))) _Float16 h4_t;
typedef __attribute__((ext_vector_type(8))) _Float16 h8_t;
typedef __attribute__((ext_vector_type(4))) float f32x4;
typedef __attribute__((ext_vector_type(4))) uint32_t u32x4;

#if __has_builtin(__builtin_amdgcn_exp2f)
#define EXP2(x) __builtin_amdgcn_exp2f(x)
#else
#define EXP2(x) exp2f(x)
#endif

// async global->LDS, 16B per lane. LDS dest must be wave-uniform base (HW adds lane*16).
__device__ __forceinline__ void gload16(const void* g, void* l) {
    __builtin_amdgcn_global_load_lds(
        (const __attribute__((address_space(1))) uint32_t*)(uintptr_t)g,
        (__attribute__((address_space(3))) uint32_t*)(uint32_t)(uintptr_t)l,
        16, 0, 0);
}

// ---------------- prep: x f32->f16  +  weights f32 [K][N] -> f16 [N][K] ----------------
__global__ __launch_bounds__(256) void prep(const float* __restrict__ x, half_t* __restrict__ xh,
                                            const float* __restrict__ wq, const float* __restrict__ wk,
                                            const float* __restrict__ wv, const float* __restrict__ wo,
                                            half_t* __restrict__ qt, half_t* __restrict__ kt,
                                            half_t* __restrict__ vt, half_t* __restrict__ ot) {
    __shared__ half_t T[32][36];
    const int bx = blockIdx.x;
    if (bx < 2048) {                       // x convert: 2048 blocks x 256 x 8 elems
        int g = (bx * 256 + threadIdx.x) * 8;
        float4 a = *(const float4*)(x + g);
        float4 b = *(const float4*)(x + g + 4);
        h8_t o = {(half_t)a.x,(half_t)a.y,(half_t)a.z,(half_t)a.w,
                  (half_t)b.x,(half_t)b.y,(half_t)b.z,(half_t)b.w};
        *(h8_t*)(xh + g) = o;
        return;
    }
    const int wb = bx - 2048;
    const float* src; half_t* dst; int Nd, t;
    if (wb < 4096)      { src = wq; dst = qt; Nd = 2048; t = wb; }
    else if (wb < 5120) { src = wk; dst = kt; Nd = 512;  t = wb - 4096; }
    else if (wb < 6144) { src = wv; dst = vt; Nd = 512;  t = wb - 5120; }
    else                { src = wo; dst = ot; Nd = 2048; t = wb - 6144; }
    const int K = 2048;
    int nt = Nd >> 5;
    int ti = t / nt, tj = t % nt;          // ti: K-tile, tj: N-tile
    int r  = threadIdx.x >> 3;
    int c4 = (threadIdx.x & 7) << 2;
    float4 v = *(const float4*)(src + (size_t)(ti*32 + r) * Nd + tj*32 + c4);
    T[r][c4+0] = (half_t)v.x; T[r][c4+1] = (half_t)v.y;
    T[r][c4+2] = (half_t)v.z; T[r][c4+3] = (half_t)v.w;
    __syncthreads();
    h4_t o = {T[c4+0][r], T[c4+1][r], T[c4+2][r], T[c4+3][r]};
    *(h4_t*)(dst + (size_t)(tj*32 + r) * K + ti*32 + c4) = o;
}

// ---------------- GEMM: C = A[M][K] @ W^T, W stored [N][K] f16 ----------------
// 64x128 tile, BK=64, 4 waves (2x2), wave tile 32x64 + 2-phase dbuf prefetch
// (1 barrier per K-step). LDS XOR-swizzled; XCD-resident bn mapping.
// QKV=1: fused Q/K/V; K/V blocks RoPE in f32 epilogue; V stores transposed via LDS.
template<int QKV, typename CT>
__global__ __launch_bounds__(256) void gemm_t(const half_t* __restrict__ A,
                                              const half_t* __restrict__ Bq,
                                              const half_t* __restrict__ Bk,
                                              const half_t* __restrict__ Bv,
                                              CT* __restrict__ Cq,
                                              half_t* __restrict__ Ck,
                                              half_t* __restrict__ Vt,
                                              const float* __restrict__ Cs,
                                              const float* __restrict__ Sn,
                                              int NB, int K) {
    constexpr int BM  = 64;
    constexpr int MI  = 2;                 // acc rows per wave (wave tile 32x64)
    constexpr int ACH = 8;                 // A chunks (1KB each)
    constexpr int PW  = 6;                 // (8 A + 16 B chunks) / 4 waves
    __shared__ half_t SMEM[2 * (64 + 128) * 64];   // 48KB: two 24KB tile-pairs
    half_t* A0 = SMEM;
    half_t* B0 = SMEM + 64 * 64;
    half_t* A1 = SMEM + 192 * 64;
    half_t* B1 = A1 + 64 * 64;
    const int tid = threadIdx.x, lane = tid & 63, wid = tid >> 6;
    const int lr = lane & 15, lg = lane >> 4;
    const int wm = wid >> 1, wn = wid & 1;
    const int bid = blockIdx.x;
    const int xcd   = bid & 7;             // HW round-robin dispatch
    const int local = bid >> 3;
    const int perx  = NB >> 3;             // bn per XCD (QKV: 3, wo: 2)
    const int bn = perx * xcd + local % perx;
    const int bm = local / perx;
    const int m0 = bm * BM;

    const half_t* W; CT* Cc; int cs, col0;
    if constexpr (QKV) {
        if (bn < 16)      { W = Bq + (size_t)bn * 128 * K;        Cc = Cq;       cs = 2048; col0 = bn * 128; }
        else if (bn < 20) { W = Bk + (size_t)(bn - 16) * 128 * K; Cc = (CT*)Ck;  cs = 512;  col0 = (bn - 16) * 128; }
        else              { W = Bv + (size_t)(bn - 20) * 128 * K; Cc = (CT*)Ck;  cs = 512;  col0 = (bn - 20) * 128; }
    } else {
        W = Bq + (size_t)bn * 128 * K; Cc = Cq; cs = NB * 128; col0 = bn * 128;
    }

    const half_t* Arow = A + (size_t)m0 * K;
    f32x4 acc[MI][4] = {};

    auto stage = [&](half_t* Ah, half_t* Bh, int k0) {
        #pragma unroll
        for (int c = 0; c < PW; c++) {
            const int chunk = wid * PW + c;                // wave-uniform, 0..23
            const int o = lane * 16;
            if (chunk < ACH) {
                const int go   = (chunk << 10) + o;
                const int row  = go >> 7;
                const int colb = (go & 127) ^ ((row & 7) << 4);
                gload16(Arow + (size_t)row * K + k0 + (colb >> 1), (char*)Ah + (chunk << 10));
            } else {
                const int go   = ((chunk - ACH) << 10) + o;
                const int row  = go >> 7;
                const int colb = (go & 127) ^ ((row & 7) << 4);
                gload16(W + (size_t)row * K + k0 + (colb >> 1), (char*)Bh + ((chunk - ACH) << 10));
            }
        }
    };

    auto compute = [&](const half_t* Ah, const half_t* Bh) {
        h8_t af[2][MI], bf[2][4];
        #pragma unroll
        for (int kk = 0; kk < 2; kk++) {
            #pragma unroll
            for (int mi = 0; mi < MI; mi++) {
                const int row = wm * 32 + mi * 16 + lr;
                const int cb  = (kk * 64 + lg * 16) ^ ((lr & 7) << 4);
                af[kk][mi] = *(const h8_t*)((const char*)Ah + row * 128 + cb);
            }
            #pragma unroll
            for (int ni = 0; ni < 4; ni++) {
                const int row = wn * 64 + ni * 16 + lr;
                const int cb  = (kk * 64 + lg * 16) ^ ((lr & 7) << 4);
                bf[kk][ni] = *(const h8_t*)((const char*)Bh + row * 128 + cb);
            }
        }
        #pragma unroll
        for (int kk = 0; kk < 2; kk++)
            #pragma unroll
            for (int mi = 0; mi < MI; mi++)
                #pragma unroll
                for (int ni = 0; ni < 4; ni++)
                    acc[mi][ni] = __builtin_amdgcn_mfma_f32_16x16x32_f16(af[kk][mi], bf[kk][ni], acc[mi][ni], 0, 0, 0);
    };

    // 2-phase pipeline: prefetch flies while current tile computes; 1 barrier/step.
    stage(A0, B0, 0);
    __syncthreads();                                   // drain prologue
    for (int k0 = 0; k0 < K; k0 += 128) {
        stage(A1, B1, k0 + 64);                        // k0+64 < K always (K mult of 128)
        compute(A0, B0);
        __syncthreads();                               // drains prefetch into A1/B1
        if (k0 + 128 < K) stage(A0, B0, k0 + 128);
        compute(A1, B1);
        __syncthreads();
    }

    if constexpr (QKV) {
        if (bn >= 16) {
            // RoPE on f32 acc: partner d^1 lives in lane lr^1 of the same row.
            #pragma unroll
            for (int ni = 0; ni < 4; ni++) {
                const int dh  = wn * 64 + ni * 16 + lr;    // d within head (0..127)
                const int p   = dh >> 1;
                const float sg = (lr & 1) ? 1.f : -1.f;
                #pragma unroll
                for (int mi = 0; mi < MI; mi++)
                    #pragma unroll
                    for (int r = 0; r < 4; r++) {
                        const int row = m0 + wm * 32 + mi * 16 + lg * 4 + r;
                        const int s = row & 1023;
                        const float c  = Cs[s * 64 + p];
                        const float si = Sn[s * 64 + p];
                        const float own = acc[mi][ni][r];
                        const float par = __shfl_xor(own, 1);
                        acc[mi][ni][r] = own * c + par * (sg * si);
                    }
            }
            if (bn >= 20) {
                // V: roped acc -> LDS [128][68] -> coalesced transposed stores to Vt
                __syncthreads();                       // staging LDS now reusable
                half_t* T = SMEM;
                constexpr int LD = 68;                 // 8B-aligned rows, ~2-way banks
                #pragma unroll
                for (int mi = 0; mi < MI; mi++)
                    #pragma unroll
                    for (int ni = 0; ni < 4; ni++) {
                        const int d  = wn * 64 + ni * 16 + lr;
                        const int s0 = wm * 32 + mi * 16 + lg * 4;
                        h4_t o = {(half_t)acc[mi][ni][0], (half_t)acc[mi][ni][1],
                                  (half_t)acc[mi][ni][2], (half_t)acc[mi][ni][3]};
                        *(h4_t*)(T + d * LD + s0) = o;
                    }
                __syncthreads();
                #pragma unroll
                for (int it = 0; it < 4; it++) {
                    const int d  = it * 32 + (tid >> 3);
                    const int c8 = (tid & 7) * 8;
                    h8_t o;
                    #pragma unroll
                    for (int e = 0; e < 8; e++) o[e] = T[d * LD + c8 + e];
                    *(h8_t*)(Vt + (size_t)(col0 + d) * 2048 + m0 + c8) = o;
                }
                return;
            }
        }
    }

    #pragma unroll
    for (int mi = 0; mi < MI; mi++)
        #pragma unroll
        for (int ni = 0; ni < 4; ni++)
            #pragma unroll
            for (int r = 0; r < 4; r++) {
                int row = m0 + wm * 32 + mi * 16 + lg * 4 + r;
                int col = col0 + wn * 64 + ni * 16 + lr;
                Cc[(size_t)row * cs + col] = (CT)acc[mi][ni][r];
            }
}

// ---------------- causal GQA flash attention: split-K, in-register P, dbuf gload ----
// Balanced piece map (17 iters per CU-triple when resident). Double-buffered K/V via
// global_load_lds: prefetch of tile kb+1 issued before compute of kb -> ONE barrier
// per iteration (drain is free: prefetch had the whole iter to land). 64KB LDS,
// 2 blocks/CU; long part0 pieces dispatch first, short part1 pieces backfill.
__global__ __launch_bounds__(256, 2) void attn10(const half_t* __restrict__ Qh,
                                                 const half_t* __restrict__ Kh,
                                                 const half_t* __restrict__ Vtg,
                                                 half_t* __restrict__ Yh,
                                                 half_t* __restrict__ Yp,
                                                 float* __restrict__ ML) {
    __shared__ half_t K0[64 * 128], V0[128 * 64];  // swizzled (256B / 128B rows)
    __shared__ half_t K1[64 * 128], V1[128 * 64];

    const int tid = threadIdx.x, lane = tid & 63, wid = tid >> 6;
    const int lr = lane & 15, lg = lane >> 4;
    const int bx = blockIdx.x;
    const int g  = bx & 7;               // (b,kvh) group -> same XCD
    const int local = bx >> 3;           // 0..95
    const int b = g >> 2, kvh = g & 3;
    const int h = kvh * 4 + (local & 3);
    const int pp = local >> 2;           // 0..23
    int qt, kb0, kb1, part; bool partial;
    if (pp < 8)       { qt = 8 + pp;      kb0 = 0; kb1 = 7;  partial = true;  part = 0; }  // 8 iters
    else if (pp < 16) { qt = pp - 8;      kb0 = 0; kb1 = qt; partial = false; part = 0; }  // qt+1 iters
    else              { qt = 15-(pp-16);  kb0 = 8; kb1 = qt; partial = true;  part = 1; }  // qt-7 iters

    const int qbase = qt * 64 + wid * 16;
    const int q     = qbase + lr;        // this lane's q-row
    const size_t kbase = (size_t)b * 1024;

    const float sc2 = 0.08838834764831845f * 1.4426950408889634f;
    h8_t qf[4];
    #pragma unroll
    for (int kk = 0; kk < 4; kk++) {
        qf[kk] = *(const h8_t*)(Qh + ((size_t)(b * 1024) + q) * 2048 + h * 128 + kk * 32 + lg * 8);
        qf[kk] = qf[kk] * (half_t)sc2;
    }

    float m = -1e30f, l = 0.f;
    f32x4 yacc[8] = {};                  // yacc[dt][r] = Y[d=dt*16+lg*4+r][q]

    auto stage = [&](half_t* kt, half_t* vb, int kb) {
        const int j = kb * 64;
        #pragma unroll
        for (int c = 0; c < 4; c++) {
            const int chunk = wid * 4 + c;
            const int o = (chunk << 10) + lane * 16;
            { const int row  = o >> 8;
              const int colb = (o & 255) ^ ((row & 7) << 4);
              gload16(Kh + (kbase + j + row) * 512 + kvh * 128 + (colb >> 1),
                      (char*)kt + (chunk << 10)); }
            { const int row  = o >> 7;
              const int colb = (o & 127) ^ ((row & 7) << 4);
              gload16(Vtg + (size_t)(kvh * 128 + row) * 2048 + kbase + j + (colb >> 1),
                      (char*)vb + (chunk << 10)); }
        }
    };

    auto iter = [&](const half_t* kt, const half_t* vb, int kb) {
        const int j = kb * 64;
        f32x4 st[4] = {};
        __builtin_amdgcn_s_setprio(1);
        #pragma unroll
        for (int t4 = 0; t4 < 4; t4++)
            #pragma unroll
            for (int kk = 0; kk < 4; kk++) {
                const int row = t4 * 16 + lr;
                const int cb  = (kk * 64 + lg * 16) ^ ((lr & 7) << 4);
                h8_t kf = *(const h8_t*)((const char*)kt + row * 256 + cb);
                st[t4] = __builtin_amdgcn_mfma_f32_16x16x32_f16(kf, qf[kk], st[t4], 0, 0, 0);
            }
        __builtin_amdgcn_s_setprio(0);
        if (kb == qt) {                  // diagonal block
            #pragma unroll
            for (int t4 = 0; t4 < 4; t4++)
                #pragma unroll
                for (int r = 0; r < 4; r++)
                    if (j + t4 * 16 + lg * 4 + r > q) st[t4][r] = -1e30f;
        }
        float mb = fmaxf(fmaxf(fmaxf(st[0][0], st[0][1]), fmaxf(st[0][2], st[0][3])),
                         fmaxf(fmaxf(st[1][0], st[1][1]), fmaxf(st[1][2], st[1][3])));
        mb = fmaxf(mb, fmaxf(fmaxf(fmaxf(st[2][0], st[2][1]), fmaxf(st[2][2], st[2][3])),
                             fmaxf(fmaxf(st[3][0], st[3][1]), fmaxf(st[3][2], st[3][3]))));
        mb = fmaxf(mb, __shfl_xor(mb, 16));
        mb = fmaxf(mb, __shfl_xor(mb, 32));
        if (!__all(mb - m <= 8.0f)) {    // defer-max (T13)
            float mn = fmaxf(m, mb);
            float al = EXP2(m - mn);
            m = mn;
            l *= al;
            #pragma unroll
            for (int dt = 0; dt < 8; dt++)
                #pragma unroll
                for (int r = 0; r < 4; r++)
                    yacc[dt][r] *= al;
        }
        float rs = 0.f;
        #pragma unroll
        for (int t4 = 0; t4 < 4; t4++)
            #pragma unroll
            for (int r = 0; r < 4; r++) {
                float p = EXP2(st[t4][r] - m);
                st[t4][r] = p;
                rs += p;
            }
        rs += __shfl_xor(rs, 16);
        rs += __shfl_xor(rs, 32);
        l += rs;
        uint32_t h2p[4][2];
        #pragma unroll
        for (int t4 = 0; t4 < 4; t4++) {
            h2p[t4][0] = __builtin_bit_cast(uint32_t,
                __builtin_amdgcn_cvt_pkrtz(st[t4][0], st[t4][1]));
            h2p[t4][1] = __builtin_bit_cast(uint32_t,
                __builtin_amdgcn_cvt_pkrtz(st[t4][2], st[t4][3]));
        }
        const int src1 = ((lg & 1) << 5) + lr;
        const int src2 = src1 + 16;
        const bool sel = (lg < 2);
        h8_t pb[2];
        #pragma unroll
        for (int c = 0; c < 2; c++) {
            uint32_t lo0 = __shfl((int)h2p[2*c][0],   src1);
            uint32_t lo1 = __shfl((int)h2p[2*c][1],   src1);
            uint32_t lo2 = __shfl((int)h2p[2*c][0],   src2);
            uint32_t lo3 = __shfl((int)h2p[2*c][1],   src2);
            uint32_t hi0 = __shfl((int)h2p[2*c+1][0], src1);
            uint32_t hi1 = __shfl((int)h2p[2*c+1][1], src1);
            uint32_t hi2 = __shfl((int)h2p[2*c+1][0], src2);
            uint32_t hi3 = __shfl((int)h2p[2*c+1][1], src2);
            u32x4 w = { sel ? lo0 : hi0, sel ? lo1 : hi1,
                        sel ? lo2 : hi2, sel ? lo3 : hi3 };
            pb[c] = __builtin_bit_cast(h8_t, w);
        }
        __builtin_amdgcn_s_setprio(1);
        #pragma unroll
        for (int dt = 0; dt < 8; dt++) {
            const int row = dt * 16 + lr;
            const int cb0 = (lg * 16) ^ ((lr & 7) << 4);
            const int cb1 = (64 + lg * 16) ^ ((lr & 7) << 4);
            h8_t v0 = *(const h8_t*)((const char*)vb + row * 128 + cb0);
            h8_t v1 = *(const h8_t*)((const char*)vb + row * 128 + cb1);
            yacc[dt] = __builtin_amdgcn_mfma_f32_16x16x32_f16(v0, pb[0], yacc[dt], 0, 0, 0);
            yacc[dt] = __builtin_amdgcn_mfma_f32_16x16x32_f16(v1, pb[1], yacc[dt], 0, 0, 0);
        }
        __builtin_amdgcn_s_setprio(0);
    };

    // dbuf gload pipeline: ONE barrier per iteration.
    stage(K0, V0, kb0);
    __syncthreads();                       // drain prologue
    for (int kb = kb0; kb <= kb1; kb += 2) {
        if (kb + 1 <= kb1) stage(K1, V1, kb + 1);   // prefetch flies during compute
        iter(K0, V0, kb);
        __syncthreads();                   // prefetch landed; all reads of K0/V0 done
        if (kb + 1 <= kb1) {
            if (kb + 2 <= kb1) stage(K0, V0, kb + 2);
            iter(K1, V1, kb + 1);
            __syncthreads();
        }
    }

    const float inv = 1.0f / l;
    if (!partial) {
        #pragma unroll
        for (int dt = 0; dt < 8; dt++) {
            h4_t o = {(half_t)(yacc[dt][0] * inv), (half_t)(yacc[dt][1] * inv),
                      (half_t)(yacc[dt][2] * inv), (half_t)(yacc[dt][3] * inv)};
            *(h4_t*)(Yh + ((size_t)(b * 1024) + q) * 2048 + h * 128 + dt * 16 + lg * 4) = o;
        }
    } else {
        const int pidx = ((b * 16 + h) * 8 + (qt - 8)) * 2 + part;
        half_t* yp = Yp + (size_t)pidx * 8192;
        const int rl = wid * 16 + lr;          // row within 64-row tile
        #pragma unroll
        for (int dt = 0; dt < 8; dt++) {
            h4_t o = {(half_t)(yacc[dt][0] * inv), (half_t)(yacc[dt][1] * inv),
                      (half_t)(yacc[dt][2] * inv), (half_t)(yacc[dt][3] * inv)};
            *(h4_t*)(yp + rl * 128 + dt * 16 + lg * 4) = o;
        }
        if (lg == 0) {
            float* ml = ML + (size_t)pidx * 128;
            ml[rl]      = m;
            ml[64 + rl] = l;
        }
    }
}

// ---------------- merge split-K partials (normalized f16 + (m,l)) ----------------
__global__ __launch_bounds__(256) void merge2(const half_t* __restrict__ Yp,
                                              const float* __restrict__ ML,
                                              half_t* __restrict__ Yh) {
    const int sidx = blockIdx.x;           // (b*16+h)*8 + (qt-8)
    const int b = sidx >> 7;
    const int rem = sidx & 127;
    const int h = rem >> 3;
    const int qt = 8 + (rem & 7);
    const int t = threadIdx.x;
    const int row = t >> 2;
    const int cg = (t & 3) * 32;
    const float* ml0 = ML + (size_t)(sidx * 2) * 128;
    const float* ml1 = ml0 + 128;
    const float m0 = ml0[row], l0 = ml0[64 + row];
    const float m1 = ml1[row], l1 = ml1[64 + row];
    const float M  = fmaxf(m0, m1);
    const float w0 = l0 * EXP2(m0 - M), w1 = l1 * EXP2(m1 - M);
    const float inv = 1.0f / (w0 + w1);
    const float a0 = w0 * inv, a1 = w1 * inv;
    const half_t* y0 = Yp + (size_t)(sidx * 2) * 8192 + row * 128 + cg;
    const half_t* y1 = y0 + 8192;
    half_t* out = Yh + ((size_t)(b * 1024 + qt * 64 + row)) * 2048 + h * 128 + cg;
    #pragma unroll
    for (int c = 0; c < 32; c += 8) {
        h8_t u = *(const h8_t*)(y0 + c);
        h8_t v = *(const h8_t*)(y1 + c);
        h8_t o;
        #pragma unroll
        for (int e = 0; e < 8; e++)
            o[e] = (half_t)(a0 * (float)u[e] + a1 * (float)v[e]);
        *(h8_t*)(out + c) = o;
    }
}

extern "C" void kernel_launch(void* const* d_in, const int* in_sizes, int n_in,
                              void* d_out, int out_size, void* d_ws, size_t ws_size,
                              hipStream_t stream) {
    const float* x  = (const float*)d_in[0];
    const float* tc = (const float*)d_in[1];
    const float* ts = (const float*)d_in[2];
    const float* wq = (const float*)d_in[3];
    const float* wk = (const float*)d_in[4];
    const float* wv = (const float*)d_in[5];
    const float* wo = (const float*)d_in[6];
    float* out = (float*)d_out;

    const size_t MD = 2048ull * 2048, MK = 2048ull * 512;
    half_t* Xh  = (half_t*)d_ws;        // 8 MB
    half_t* Qh  = Xh  + MD;             // 8 MB
    half_t* Kh  = Qh  + MD;             // 2 MB
    half_t* Vh  = Kh  + MK;             // 2 MB (unused, layout stability)
    half_t* Vt  = Vh  + MK;             // 2 MB
    half_t* Yh  = Vt  + MK;             // 8 MB
    half_t* wqt = Yh  + MD;             // 8 MB
    half_t* wkt = wqt + MD;             // 2 MB
    half_t* wvt = wkt + MK;             // 2 MB
    half_t* wot = wvt + MK;             // 8 MB
    half_t* Yp  = wot + MD;             // 512 x 64 x 128 f16 = 8 MB
    float*  ML  = (float*)(Yp + 512ull * 8192);  // 512 x 128 f32 = 256 KB

    prep<<<12288, 256, 0, stream>>>(x, Xh, wq, wk, wv, wo, wqt, wkt, wvt, wot);
    gemm_t<1, half_t><<<768, 256, 0, stream>>>(Xh, wqt, wkt, wvt, Qh, Kh, Vt, tc, ts, 24, 2048);
    attn10<<<768, 256, 0, stream>>>(Qh, Kh, Vt, Yh, Yp, ML);
    merge2<<<256, 256, 0, stream>>>(Yp, ML, Yh);
    gemm_t<0, float><<<512, 256, 0, stream>>>(Yh, wot, nullptr, nullptr, out, nullptr, nullptr, nullptr, nullptr, 16, 2048);
}

// Round 17
// 101.968 us; speedup vs baseline: 1.0277x; 1.0277x over previous
//
#include <hip/hip_runtime.h>
#include <hip/hip_bf16.h>
#include <stdint.h>
#include <math.h>

typedef _Float16 half_t;
typedef __attribute__((ext_vector_type(2))) _Float16 h2_t;
typedef __attribute__((ext_vector_type(4))) _Float16 h4_t;
typedef __attribute__((ext_vector_type(8))) _Float16 h8_t;
typedef __attribute__((ext_vector_type(4))) float f32x4;
typedef __attribute__((ext_vector_type(4))) uint32_t u32x4;

#if __has_builtin(__builtin_amdgcn_exp2f)
#define EXP2(x) __builtin_amdgcn_exp2f(x)
#else
#define EXP2(x) exp2f(x)
#endif

// async global->LDS, 16B per lane. LDS dest must be wave-uniform base (HW adds lane*16).
__device__ __forceinline__ void gload16(const void* g, void* l) {
    __builtin_amdgcn_global_load_lds(
        (const __attribute__((address_space(1))) uint32_t*)(uintptr_t)g,
        (__attribute__((address_space(3))) uint32_t*)(uint32_t)(uintptr_t)l,
        16, 0, 0);
}

// ---------------- prep: x f32->f16  +  weights f32 [K][N] -> f16 [N][K] ----------------
__global__ __launch_bounds__(256) void prep(const float* __restrict__ x, half_t* __restrict__ xh,
                                            const float* __restrict__ wq, const float* __restrict__ wk,
                                            const float* __restrict__ wv, const float* __restrict__ wo,
                                            half_t* __restrict__ qt, half_t* __restrict__ kt,
                                            half_t* __restrict__ vt, half_t* __restrict__ ot) {
    __shared__ half_t T[32][36];
    const int bx = blockIdx.x;
    if (bx < 2048) {                       // x convert: 2048 blocks x 256 x 8 elems
        int g = (bx * 256 + threadIdx.x) * 8;
        float4 a = *(const float4*)(x + g);
        float4 b = *(const float4*)(x + g + 4);
        h8_t o = {(half_t)a.x,(half_t)a.y,(half_t)a.z,(half_t)a.w,
                  (half_t)b.x,(half_t)b.y,(half_t)b.z,(half_t)b.w};
        *(h8_t*)(xh + g) = o;
        return;
    }
    const int wb = bx - 2048;
    const float* src; half_t* dst; int Nd, t;
    if (wb < 4096)      { src = wq; dst = qt; Nd = 2048; t = wb; }
    else if (wb < 5120) { src = wk; dst = kt; Nd = 512;  t = wb - 4096; }
    else if (wb < 6144) { src = wv; dst = vt; Nd = 512;  t = wb - 5120; }
    else                { src = wo; dst = ot; Nd = 2048; t = wb - 6144; }
    const int K = 2048;
    int nt = Nd >> 5;
    int ti = t / nt, tj = t % nt;          // ti: K-tile, tj: N-tile
    int r  = threadIdx.x >> 3;
    int c4 = (threadIdx.x & 7) << 2;
    float4 v = *(const float4*)(src + (size_t)(ti*32 + r) * Nd + tj*32 + c4);
    T[r][c4+0] = (half_t)v.x; T[r][c4+1] = (half_t)v.y;
    T[r][c4+2] = (half_t)v.z; T[r][c4+3] = (half_t)v.w;
    __syncthreads();
    h4_t o = {T[c4+0][r], T[c4+1][r], T[c4+2][r], T[c4+3][r]};
    *(h4_t*)(dst + (size_t)(tj*32 + r) * K + ti*32 + c4) = o;
}

// ---------------- GEMM: C = A[M][K] @ W^T, W stored [N][K] f16 ----------------
// 64x128 tile, BK=64, 4 waves (2x2), wave tile 32x64 + 2-phase dbuf prefetch
// (1 barrier per K-step). LDS XOR-swizzled; XCD-resident bn mapping.
// QKV=1: fused Q/K/V; K/V blocks RoPE in f32 epilogue; V stores transposed via LDS.
template<int QKV, typename CT>
__global__ __launch_bounds__(256) void gemm_t(const half_t* __restrict__ A,
                                              const half_t* __restrict__ Bq,
                                              const half_t* __restrict__ Bk,
                                              const half_t* __restrict__ Bv,
                                              CT* __restrict__ Cq,
                                              half_t* __restrict__ Ck,
                                              half_t* __restrict__ Vt,
                                              const float* __restrict__ Cs,
                                              const float* __restrict__ Sn,
                                              int NB, int K) {
    constexpr int BM  = 64;
    constexpr int MI  = 2;                 // acc rows per wave (wave tile 32x64)
    constexpr int ACH = 8;                 // A chunks (1KB each)
    constexpr int PW  = 6;                 // (8 A + 16 B chunks) / 4 waves
    __shared__ half_t SMEM[2 * (64 + 128) * 64];   // 48KB: two 24KB tile-pairs
    half_t* A0 = SMEM;
    half_t* B0 = SMEM + 64 * 64;
    half_t* A1 = SMEM + 192 * 64;
    half_t* B1 = A1 + 64 * 64;
    const int tid = threadIdx.x, lane = tid & 63, wid = tid >> 6;
    const int lr = lane & 15, lg = lane >> 4;
    const int wm = wid >> 1, wn = wid & 1;
    const int bid = blockIdx.x;
    const int xcd   = bid & 7;             // HW round-robin dispatch
    const int local = bid >> 3;
    const int perx  = NB >> 3;             // bn per XCD (QKV: 3, wo: 2)
    const int bn = perx * xcd + local % perx;
    const int bm = local / perx;
    const int m0 = bm * BM;

    const half_t* W; CT* Cc; int cs, col0;
    if constexpr (QKV) {
        if (bn < 16)      { W = Bq + (size_t)bn * 128 * K;        Cc = Cq;       cs = 2048; col0 = bn * 128; }
        else if (bn < 20) { W = Bk + (size_t)(bn - 16) * 128 * K; Cc = (CT*)Ck;  cs = 512;  col0 = (bn - 16) * 128; }
        else              { W = Bv + (size_t)(bn - 20) * 128 * K; Cc = (CT*)Ck;  cs = 512;  col0 = (bn - 20) * 128; }
    } else {
        W = Bq + (size_t)bn * 128 * K; Cc = Cq; cs = NB * 128; col0 = bn * 128;
    }

    const half_t* Arow = A + (size_t)m0 * K;
    f32x4 acc[MI][4] = {};

    auto stage = [&](half_t* Ah, half_t* Bh, int k0) {
        #pragma unroll
        for (int c = 0; c < PW; c++) {
            const int chunk = wid * PW + c;                // wave-uniform, 0..23
            const int o = lane * 16;
            if (chunk < ACH) {
                const int go   = (chunk << 10) + o;
                const int row  = go >> 7;
                const int colb = (go & 127) ^ ((row & 7) << 4);
                gload16(Arow + (size_t)row * K + k0 + (colb >> 1), (char*)Ah + (chunk << 10));
            } else {
                const int go   = ((chunk - ACH) << 10) + o;
                const int row  = go >> 7;
                const int colb = (go & 127) ^ ((row & 7) << 4);
                gload16(W + (size_t)row * K + k0 + (colb >> 1), (char*)Bh + ((chunk - ACH) << 10));
            }
        }
    };

    auto compute = [&](const half_t* Ah, const half_t* Bh) {
        h8_t af[2][MI], bf[2][4];
        #pragma unroll
        for (int kk = 0; kk < 2; kk++) {
            #pragma unroll
            for (int mi = 0; mi < MI; mi++) {
                const int row = wm * 32 + mi * 16 + lr;
                const int cb  = (kk * 64 + lg * 16) ^ ((lr & 7) << 4);
                af[kk][mi] = *(const h8_t*)((const char*)Ah + row * 128 + cb);
            }
            #pragma unroll
            for (int ni = 0; ni < 4; ni++) {
                const int row = wn * 64 + ni * 16 + lr;
                const int cb  = (kk * 64 + lg * 16) ^ ((lr & 7) << 4);
                bf[kk][ni] = *(const h8_t*)((const char*)Bh + row * 128 + cb);
            }
        }
        #pragma unroll
        for (int kk = 0; kk < 2; kk++)
            #pragma unroll
            for (int mi = 0; mi < MI; mi++)
                #pragma unroll
                for (int ni = 0; ni < 4; ni++)
                    acc[mi][ni] = __builtin_amdgcn_mfma_f32_16x16x32_f16(af[kk][mi], bf[kk][ni], acc[mi][ni], 0, 0, 0);
    };

    // 2-phase pipeline: prefetch flies while current tile computes; 1 barrier/step.
    stage(A0, B0, 0);
    __syncthreads();                                   // drain prologue
    for (int k0 = 0; k0 < K; k0 += 128) {
        stage(A1, B1, k0 + 64);                        // k0+64 < K always (K mult of 128)
        compute(A0, B0);
        __syncthreads();                               // drains prefetch into A1/B1
        if (k0 + 128 < K) stage(A0, B0, k0 + 128);
        compute(A1, B1);
        __syncthreads();
    }

    if constexpr (QKV) {
        if (bn >= 16) {
            // RoPE on f32 acc: partner d^1 lives in lane lr^1 of the same row.
            #pragma unroll
            for (int ni = 0; ni < 4; ni++) {
                const int dh  = wn * 64 + ni * 16 + lr;    // d within head (0..127)
                const int p   = dh >> 1;
                const float sg = (lr & 1) ? 1.f : -1.f;
                #pragma unroll
                for (int mi = 0; mi < MI; mi++)
                    #pragma unroll
                    for (int r = 0; r < 4; r++) {
                        const int row = m0 + wm * 32 + mi * 16 + lg * 4 + r;
                        const int s = row & 1023;
                        const float c  = Cs[s * 64 + p];
                        const float si = Sn[s * 64 + p];
                        const float own = acc[mi][ni][r];
                        const float par = __shfl_xor(own, 1);
                        acc[mi][ni][r] = own * c + par * (sg * si);
                    }
            }
            if (bn >= 20) {
                // V: roped acc -> LDS [128][68] -> coalesced transposed stores to Vt
                __syncthreads();                       // staging LDS now reusable
                half_t* T = SMEM;
                constexpr int LD = 68;                 // 8B-aligned rows, ~2-way banks
                #pragma unroll
                for (int mi = 0; mi < MI; mi++)
                    #pragma unroll
                    for (int ni = 0; ni < 4; ni++) {
                        const int d  = wn * 64 + ni * 16 + lr;
                        const int s0 = wm * 32 + mi * 16 + lg * 4;
                        h4_t o = {(half_t)acc[mi][ni][0], (half_t)acc[mi][ni][1],
                                  (half_t)acc[mi][ni][2], (half_t)acc[mi][ni][3]};
                        *(h4_t*)(T + d * LD + s0) = o;
                    }
                __syncthreads();
                #pragma unroll
                for (int it = 0; it < 4; it++) {
                    const int d  = it * 32 + (tid >> 3);
                    const int c8 = (tid & 7) * 8;
                    h8_t o;
                    #pragma unroll
                    for (int e = 0; e < 8; e++) o[e] = T[d * LD + c8 + e];
                    *(h8_t*)(Vt + (size_t)(col0 + d) * 2048 + m0 + c8) = o;
                }
                return;
            }
        }
    }

    #pragma unroll
    for (int mi = 0; mi < MI; mi++)
        #pragma unroll
        for (int ni = 0; ni < 4; ni++)
            #pragma unroll
            for (int r = 0; r < 4; r++) {
                int row = m0 + wm * 32 + mi * 16 + lg * 4 + r;
                int col = col0 + wn * 64 + ni * 16 + lr;
                Cc[(size_t)row * cs + col] = (CT)acc[mi][ni][r];
            }
}

// ---------------- causal GQA flash attention: split-K, in-register P, T14 prefetch ----
// Balanced piece map: each CU hosts {part0(8 iters), direct qt=pp (pp+1), part1 of
// qt=15-pp (8-pp)} -> exactly 17 iters per CU.
__global__ __launch_bounds__(256, 3) void attn9(const half_t* __restrict__ Qh,
                                                const half_t* __restrict__ Kh,
                                                const half_t* __restrict__ Vtg,
                                                half_t* __restrict__ Yh,
                                                half_t* __restrict__ Yp,
                                                float* __restrict__ ML) {
    __shared__ half_t K0[64 * 128];      // swizzled rows of 256B
    __shared__ half_t V0[128 * 64];      // swizzled rows of 128B

    const int tid = threadIdx.x, lane = tid & 63, wid = tid >> 6;
    const int lr = lane & 15, lg = lane >> 4;
    const int bx = blockIdx.x;
    const int g  = bx & 7;               // (b,kvh) group -> same XCD
    const int local = bx >> 3;           // 0..95
    const int b = g >> 2, kvh = g & 3;
    const int h = kvh * 4 + (local & 3);
    const int pp = local >> 2;           // 0..23
    int qt, kb0, kb1, part; bool partial;
    if (pp < 8)       { qt = 8 + pp;      kb0 = 0; kb1 = 7;  partial = true;  part = 0; }  // 8 iters
    else if (pp < 16) { qt = pp - 8;      kb0 = 0; kb1 = qt; partial = false; part = 0; }  // qt+1 iters
    else              { qt = 15-(pp-16);  kb0 = 8; kb1 = qt; partial = true;  part = 1; }  // qt-7 iters
    // CU triple {pp, pp+8, pp+16}: 8 + (pp+1) + (8-pp) = 17 iters, every CU.

    const int qbase = qt * 64 + wid * 16;
    const int q     = qbase + lr;        // this lane's q-row
    const size_t kbase = (size_t)b * 1024;

    const float sc2 = 0.08838834764831845f * 1.4426950408889634f;
    h8_t qf[4];
    #pragma unroll
    for (int kk = 0; kk < 4; kk++) {
        qf[kk] = *(const h8_t*)(Qh + ((size_t)(b * 1024) + q) * 2048 + h * 128 + kk * 32 + lg * 8);
        qf[kk] = qf[kk] * (half_t)sc2;
    }

    float m = -1e30f, l = 0.f;
    f32x4 yacc[8] = {};                  // yacc[dt][r] = Y[d=dt*16+lg*4+r][q]

    {   // prologue stage via gload16
        const int j = kb0 * 64;
        #pragma unroll
        for (int c = 0; c < 4; c++) {
            const int chunk = wid * 4 + c;
            const int o = (chunk << 10) + lane * 16;
            { const int row  = o >> 8;
              const int colb = (o & 255) ^ ((row & 7) << 4);
              gload16(Kh + (kbase + j + row) * 512 + kvh * 128 + (colb >> 1),
                      (char*)K0 + (chunk << 10)); }
            { const int row  = o >> 7;
              const int colb = (o & 127) ^ ((row & 7) << 4);
              gload16(Vtg + (size_t)(kvh * 128 + row) * 2048 + kbase + j + (colb >> 1),
                      (char*)V0 + (chunk << 10)); }
        }
    }
    __syncthreads();                     // drain prologue

    for (int kb = kb0; kb <= kb1; kb++) {
        // T14: issue NEXT tile's loads into registers before compute
        const bool pf = (kb + 1 <= kb1);
        h8_t kpre[4], vpre[4];
        if (pf) {
            const int j2 = (kb + 1) * 64;
            #pragma unroll
            for (int c = 0; c < 4; c++) {
                const int chunk = wid * 4 + c;
                const int o = (chunk << 10) + lane * 16;
                { const int row  = o >> 8;
                  const int colb = (o & 255) ^ ((row & 7) << 4);
                  kpre[c] = *(const h8_t*)(Kh + (kbase + j2 + row) * 512 + kvh * 128 + (colb >> 1)); }
                { const int row  = o >> 7;
                  const int colb = (o & 127) ^ ((row & 7) << 4);
                  vpre[c] = *(const h8_t*)(Vtg + (size_t)(kvh * 128 + row) * 2048 + kbase + j2 + (colb >> 1)); }
            }
        }

        const int j = kb * 64;
        f32x4 st[4] = {};
        __builtin_amdgcn_s_setprio(1);
        #pragma unroll
        for (int t4 = 0; t4 < 4; t4++)
            #pragma unroll
            for (int kk = 0; kk < 4; kk++) {
                const int row = t4 * 16 + lr;
                const int cb  = (kk * 64 + lg * 16) ^ ((lr & 7) << 4);
                h8_t kf = *(const h8_t*)((const char*)K0 + row * 256 + cb);
                st[t4] = __builtin_amdgcn_mfma_f32_16x16x32_f16(kf, qf[kk], st[t4], 0, 0, 0);
            }
        __builtin_amdgcn_s_setprio(0);
        if (kb == qt) {                  // diagonal block
            #pragma unroll
            for (int t4 = 0; t4 < 4; t4++)
                #pragma unroll
                for (int r = 0; r < 4; r++)
                    if (j + t4 * 16 + lg * 4 + r > q) st[t4][r] = -1e30f;
        }
        float mb = fmaxf(fmaxf(fmaxf(st[0][0], st[0][1]), fmaxf(st[0][2], st[0][3])),
                         fmaxf(fmaxf(st[1][0], st[1][1]), fmaxf(st[1][2], st[1][3])));
        mb = fmaxf(mb, fmaxf(fmaxf(fmaxf(st[2][0], st[2][1]), fmaxf(st[2][2], st[2][3])),
                             fmaxf(fmaxf(st[3][0], st[3][1]), fmaxf(st[3][2], st[3][3]))));
        mb = fmaxf(mb, __shfl_xor(mb, 16));
        mb = fmaxf(mb, __shfl_xor(mb, 32));
        if (!__all(mb - m <= 8.0f)) {    // defer-max (T13)
            float mn = fmaxf(m, mb);
            float al = EXP2(m - mn);
            m = mn;
            l *= al;
            #pragma unroll
            for (int dt = 0; dt < 8; dt++)
                #pragma unroll
                for (int r = 0; r < 4; r++)
                    yacc[dt][r] *= al;
        }
        float rs = 0.f;
        #pragma unroll
        for (int t4 = 0; t4 < 4; t4++)
            #pragma unroll
            for (int r = 0; r < 4; r++) {
                float p = EXP2(st[t4][r] - m);
                st[t4][r] = p;
                rs += p;
            }
        rs += __shfl_xor(rs, 16);
        rs += __shfl_xor(rs, 32);
        l += rs;
        uint32_t h2p[4][2];
        #pragma unroll
        for (int t4 = 0; t4 < 4; t4++) {
            h2p[t4][0] = __builtin_bit_cast(uint32_t,
                __builtin_amdgcn_cvt_pkrtz(st[t4][0], st[t4][1]));
            h2p[t4][1] = __builtin_bit_cast(uint32_t,
                __builtin_amdgcn_cvt_pkrtz(st[t4][2], st[t4][3]));
        }
        const int src1 = ((lg & 1) << 5) + lr;
        const int src2 = src1 + 16;
        const bool sel = (lg < 2);
        h8_t pb[2];
        #pragma unroll
        for (int c = 0; c < 2; c++) {
            uint32_t lo0 = __shfl((int)h2p[2*c][0],   src1);
            uint32_t lo1 = __shfl((int)h2p[2*c][1],   src1);
            uint32_t lo2 = __shfl((int)h2p[2*c][0],   src2);
            uint32_t lo3 = __shfl((int)h2p[2*c][1],   src2);
            uint32_t hi0 = __shfl((int)h2p[2*c+1][0], src1);
            uint32_t hi1 = __shfl((int)h2p[2*c+1][1], src1);
            uint32_t hi2 = __shfl((int)h2p[2*c+1][0], src2);
            uint32_t hi3 = __shfl((int)h2p[2*c+1][1], src2);
            u32x4 w = { sel ? lo0 : hi0, sel ? lo1 : hi1,
                        sel ? lo2 : hi2, sel ? lo3 : hi3 };
            pb[c] = __builtin_bit_cast(h8_t, w);
        }
        __builtin_amdgcn_s_setprio(1);
        #pragma unroll
        for (int dt = 0; dt < 8; dt++) {
            const int row = dt * 16 + lr;
            const int cb0 = (lg * 16) ^ ((lr & 7) << 4);
            const int cb1 = (64 + lg * 16) ^ ((lr & 7) << 4);
            h8_t v0 = *(const h8_t*)((const char*)V0 + row * 128 + cb0);
            h8_t v1 = *(const h8_t*)((const char*)V0 + row * 128 + cb1);
            yacc[dt] = __builtin_amdgcn_mfma_f32_16x16x32_f16(v0, pb[0], yacc[dt], 0, 0, 0);
            yacc[dt] = __builtin_amdgcn_mfma_f32_16x16x32_f16(v1, pb[1], yacc[dt], 0, 0, 0);
        }
        __builtin_amdgcn_s_setprio(0);

        __syncthreads();                 // all waves done reading K0/V0
        if (pf) {                        // write prefetched tile (vmcnt wait lands here)
            #pragma unroll
            for (int c = 0; c < 4; c++) {
                const int chunk = wid * 4 + c;
                const int o = (chunk << 10) + lane * 16;
                *(h8_t*)((char*)K0 + o) = kpre[c];
                *(h8_t*)((char*)V0 + o) = vpre[c];
            }
            __syncthreads();             // LDS ready for next iter
        }
    }

    const float inv = 1.0f / l;
    if (!partial) {
        #pragma unroll
        for (int dt = 0; dt < 8; dt++) {
            h4_t o = {(half_t)(yacc[dt][0] * inv), (half_t)(yacc[dt][1] * inv),
                      (half_t)(yacc[dt][2] * inv), (half_t)(yacc[dt][3] * inv)};
            *(h4_t*)(Yh + ((size_t)(b * 1024) + q) * 2048 + h * 128 + dt * 16 + lg * 4) = o;
        }
    } else {
        const int pidx = ((b * 16 + h) * 8 + (qt - 8)) * 2 + part;
        half_t* yp = Yp + (size_t)pidx * 8192;
        const int rl = wid * 16 + lr;          // row within 64-row tile
        #pragma unroll
        for (int dt = 0; dt < 8; dt++) {
            h4_t o = {(half_t)(yacc[dt][0] * inv), (half_t)(yacc[dt][1] * inv),
                      (half_t)(yacc[dt][2] * inv), (half_t)(yacc[dt][3] * inv)};
            *(h4_t*)(yp + rl * 128 + dt * 16 + lg * 4) = o;
        }
        if (lg == 0) {
            float* ml = ML + (size_t)pidx * 128;
            ml[rl]      = m;
            ml[64 + rl] = l;
        }
    }
}

// ---------------- merge split-K partials (normalized f16 + (m,l)) ----------------
__global__ __launch_bounds__(256) void merge2(const half_t* __restrict__ Yp,
                                              const float* __restrict__ ML,
                                              half_t* __restrict__ Yh) {
    const int sidx = blockIdx.x;           // (b*16+h)*8 + (qt-8)
    const int b = sidx >> 7;
    const int rem = sidx & 127;
    const int h = rem >> 3;
    const int qt = 8 + (rem & 7);
    const int t = threadIdx.x;
    const int row = t >> 2;
    const int cg = (t & 3) * 32;
    const float* ml0 = ML + (size_t)(sidx * 2) * 128;
    const float* ml1 = ml0 + 128;
    const float m0 = ml0[row], l0 = ml0[64 + row];
    const float m1 = ml1[row], l1 = ml1[64 + row];
    const float M  = fmaxf(m0, m1);
    const float w0 = l0 * EXP2(m0 - M), w1 = l1 * EXP2(m1 - M);
    const float inv = 1.0f / (w0 + w1);
    const float a0 = w0 * inv, a1 = w1 * inv;
    const half_t* y0 = Yp + (size_t)(sidx * 2) * 8192 + row * 128 + cg;
    const half_t* y1 = y0 + 8192;
    half_t* out = Yh + ((size_t)(b * 1024 + qt * 64 + row)) * 2048 + h * 128 + cg;
    #pragma unroll
    for (int c = 0; c < 32; c += 8) {
        h8_t u = *(const h8_t*)(y0 + c);
        h8_t v = *(const h8_t*)(y1 + c);
        h8_t o;
        #pragma unroll
        for (int e = 0; e < 8; e++)
            o[e] = (half_t)(a0 * (float)u[e] + a1 * (float)v[e]);
        *(h8_t*)(out + c) = o;
    }
}

extern "C" void kernel_launch(void* const* d_in, const int* in_sizes, int n_in,
                              void* d_out, int out_size, void* d_ws, size_t ws_size,
                              hipStream_t stream) {
    const float* x  = (const float*)d_in[0];
    const float* tc = (const float*)d_in[1];
    const float* ts = (const float*)d_in[2];
    const float* wq = (const float*)d_in[3];
    const float* wk = (const float*)d_in[4];
    const float* wv = (const float*)d_in[5];
    const float* wo = (const float*)d_in[6];
    float* out = (float*)d_out;

    const size_t MD = 2048ull * 2048, MK = 2048ull * 512;
    half_t* Xh  = (half_t*)d_ws;        // 8 MB
    half_t* Qh  = Xh  + MD;             // 8 MB
    half_t* Kh  = Qh  + MD;             // 2 MB
    half_t* Vh  = Kh  + MK;             // 2 MB (unused, layout stability)
    half_t* Vt  = Vh  + MK;             // 2 MB
    half_t* Yh  = Vt  + MK;             // 8 MB
    half_t* wqt = Yh  + MD;             // 8 MB
    half_t* wkt = wqt + MD;             // 2 MB
    half_t* wvt = wkt + MK;             // 2 MB
    half_t* wot = wvt + MK;             // 8 MB
    half_t* Yp  = wot + MD;             // 512 x 64 x 128 f16 = 8 MB
    float*  ML  = (float*)(Yp + 512ull * 8192);  // 512 x 128 f32 = 256 KB

    prep<<<12288, 256, 0, stream>>>(x, Xh, wq, wk, wv, wo, wqt, wkt, wvt, wot);
    gemm_t<1, half_t><<<768, 256, 0, stream>>>(Xh, wqt, wkt, wvt, Qh, Kh, Vt, tc, ts, 24, 2048);
    attn9<<<768, 256, 0, stream>>>(Qh, Kh, Vt, Yh, Yp, ML);
    merge2<<<256, 256, 0, stream>>>(Yp, ML, Yh);
    gemm_t<0, float><<<512, 256, 0, stream>>>(Yh, wot, nullptr, nullptr, out, nullptr, nullptr, nullptr, nullptr, 16, 2048);
}